// Round 3
// baseline (560.874 us; speedup 1.0000x reference)
//
#include <hip/hip_runtime.h>
#include <stdint.h>
#include <math.h>

using short8   = __attribute__((ext_vector_type(8))) short;
using ushort4v = __attribute__((ext_vector_type(4))) unsigned short;
using f32x4    = __attribute__((ext_vector_type(4))) float;

#define B_ 2
#define S_ 64
#define K_ 64
#define D_ 256
#define C_ 32
#define N_ 4096  /* S_*K_ */

__device__ __forceinline__ float b2f(unsigned short u) {
    unsigned int v = ((unsigned int)u) << 16;
    return __builtin_bit_cast(float, v);
}
__device__ __forceinline__ unsigned short f2b(float f) {   // RNE f32->bf16
    unsigned int x = __builtin_bit_cast(unsigned int, f);
    x += 0x7fffu + ((x >> 16) & 1u);
    return (unsigned short)(x >> 16);
}

// load 8 consecutive f32, produce hi/lo split-bf16 fragments (hi+lo ~ 2^-17 rel)
__device__ __forceinline__ void cvt8(const float* p, short8& hi, short8& lo) {
    f32x4 a = *(const f32x4*)p;
    f32x4 c = *(const f32x4*)(p + 4);
#pragma unroll
    for (int e = 0; e < 4; ++e) {
        unsigned short h0 = f2b(a[e]);
        hi[e]     = (short)h0; lo[e]     = (short)f2b(a[e] - b2f(h0));
        unsigned short h1 = f2b(c[e]);
        hi[e + 4] = (short)h1; lo[e + 4] = (short)f2b(c[e] - b2f(h1));
    }
}
__device__ __forceinline__ void cvt8h(const float* p, short8& hi) {
    f32x4 a = *(const f32x4*)p;
    f32x4 c = *(const f32x4*)(p + 4);
#pragma unroll
    for (int e = 0; e < 4; ++e) {
        hi[e]     = (short)f2b(a[e]);
        hi[e + 4] = (short)f2b(c[e]);
    }
}

// ---------------------------------------------------------------------------
// Kernel 1: QKV projections from f32 x, W. One wave = 16-token x 16-channel.
// ct 0-1 -> Q (hi/lo split), 2-3 -> K (hi/lo), 4-19 -> V (single bf16).
// Q,K stored [B][N][C] bf16 (hi and lo planes); V stored [B][D][N] bf16.
// ---------------------------------------------------------------------------
__global__ __launch_bounds__(256) void qkv_kernel(
    const float* __restrict__ x,
    const float* __restrict__ Wq, const float* __restrict__ bq,
    const float* __restrict__ Wk, const float* __restrict__ bk,
    const float* __restrict__ Wv, const float* __restrict__ bv,
    unsigned short* __restrict__ Qh, unsigned short* __restrict__ Ql,
    unsigned short* __restrict__ Kh, unsigned short* __restrict__ Kl,
    unsigned short* __restrict__ Vm)
{
    int widx = blockIdx.x * 4 + (threadIdx.x >> 6);   // 0..10239
    int lane = threadIdx.x & 63;
    int ttile = widx / 20;        // token tile of 16 (0..511)
    int ct    = widx % 20;        // channel tile
    int b  = ttile >> 8;
    int n0 = (ttile & 255) << 4;
    int col = lane & 15, g = lane >> 4;

    int n = n0 + col;
    int s = n & (S_ - 1), kk = n >> 6;
    const float* xrow = x + (((size_t)(b * S_ + s)) * K_ + kk) * D_;

    f32x4 acc = {0.f, 0.f, 0.f, 0.f};

    if (ct < 4) {                       // Q or K: hi/lo split path
        const float* W; const float* bias; int c0;
        if (ct < 2) { W = Wq; bias = bq; c0 = ct * 16; }
        else        { W = Wk; bias = bk; c0 = (ct - 2) * 16; }
        const float* wrow = W + (size_t)(c0 + col) * D_;
#pragma unroll
        for (int dc = 0; dc < 8; ++dc) {
            short8 xh, xl, wh, wl;
            cvt8(xrow + dc * 32 + g * 8, xh, xl);
            cvt8(wrow + dc * 32 + g * 8, wh, wl);
            acc = __builtin_amdgcn_mfma_f32_16x16x32_bf16(xl, wh, acc, 0, 0, 0);
            acc = __builtin_amdgcn_mfma_f32_16x16x32_bf16(xh, wl, acc, 0, 0, 0);
            acc = __builtin_amdgcn_mfma_f32_16x16x32_bf16(xh, wh, acc, 0, 0, 0);
        }
        float bb = bias[c0 + col];
        unsigned short* Th = (ct < 2) ? Qh : Kh;
        unsigned short* Tl = (ct < 2) ? Ql : Kl;
#pragma unroll
        for (int r = 0; r < 4; ++r) {
            int tok = n0 + g * 4 + r;
            float v = acc[r] + bb;
            unsigned short h = f2b(v);
            size_t idx = ((size_t)b * N_ + tok) * C_ + c0 + col;
            Th[idx] = h;
            Tl[idx] = f2b(v - b2f(h));
        }
    } else {                            // V: single-bf16 path
        int c0 = (ct - 4) * 16;
        const float* wrow = Wv + (size_t)(c0 + col) * D_;
#pragma unroll
        for (int dc = 0; dc < 8; ++dc) {
            short8 xh, wh;
            cvt8h(xrow + dc * 32 + g * 8, xh);
            cvt8h(wrow + dc * 32 + g * 8, wh);
            acc = __builtin_amdgcn_mfma_f32_16x16x32_bf16(xh, wh, acc, 0, 0, 0);
        }
        float bb = bv[c0 + col];
        ushort4v st;
#pragma unroll
        for (int r = 0; r < 4; ++r) st[r] = f2b(acc[r] + bb);
        *(ushort4v*)(Vm + ((size_t)b * D_ + c0 + col) * N_ + n0 + g * 4) = st;
    }
}

// ---------------------------------------------------------------------------
// Kernel 2: flash attention (no-max softmax: scores bounded ~34, exp in f32
// never overflows; l <= 2.4e18 finite) + residual + permuted f32 store.
// 512 blocks x 1 wave; wave owns 16 queries, streams 4096 keys in 32-chunks.
// Swapped QK^T with hi/lo split-bf16 (3-MFMA chain): D[key][q].
// ---------------------------------------------------------------------------
__global__ __launch_bounds__(64) void attn_kernel(
    const unsigned short* __restrict__ Qh, const unsigned short* __restrict__ Ql,
    const unsigned short* __restrict__ Kh, const unsigned short* __restrict__ Kl,
    const unsigned short* __restrict__ Vm, const float* __restrict__ x,
    const float* __restrict__ gamma_p, float* __restrict__ out)
{
    __shared__ unsigned short plds[16 * 40];   // P^T buffer, padded stride 40

    int bid = blockIdx.x;                   // 512 % 8 == 0 -> bijective swizzle
    int swz = (bid & 7) * 64 + (bid >> 3);
    int b    = swz >> 8;
    int q0   = (swz & 255) << 4;
    int lane = threadIdx.x & 63;
    int col = lane & 15, g = lane >> 4;

    // Q fragments: B[c][q] = Q[q][c], lane col = q, k = g*8+e
    size_t qoff = ((size_t)b * N_ + q0 + col) * C_ + g * 8;
    short8 qfh = *(const short8*)(Qh + qoff);
    short8 qfl = *(const short8*)(Ql + qoff);

    f32x4 acc[16];
#pragma unroll
    for (int t = 0; t < 16; ++t) acc[t] = (f32x4){0.f, 0.f, 0.f, 0.f};
    float l_run = 0.f;

    const unsigned short* kbh = Kh + (size_t)b * N_ * C_;
    const unsigned short* kbl = Kl + (size_t)b * N_ * C_;
    const unsigned short* vb  = Vm + (size_t)b * D_ * N_;

    for (int j0 = 0; j0 < N_; j0 += 32) {
        size_t k0 = (size_t)(j0 + col) * C_ + g * 8;
        size_t k1 = (size_t)(j0 + 16 + col) * C_ + g * 8;
        short8 kh0 = *(const short8*)(kbh + k0);
        short8 kl0 = *(const short8*)(kbl + k0);
        short8 kh1 = *(const short8*)(kbh + k1);
        short8 kl1 = *(const short8*)(kbl + k1);

        f32x4 z = {0.f, 0.f, 0.f, 0.f};
        f32x4 s0 = __builtin_amdgcn_mfma_f32_16x16x32_bf16(kl0, qfh, z, 0, 0, 0);
        s0 = __builtin_amdgcn_mfma_f32_16x16x32_bf16(kh0, qfl, s0, 0, 0, 0);
        s0 = __builtin_amdgcn_mfma_f32_16x16x32_bf16(kh0, qfh, s0, 0, 0, 0);
        f32x4 s1 = __builtin_amdgcn_mfma_f32_16x16x32_bf16(kl1, qfh, z, 0, 0, 0);
        s1 = __builtin_amdgcn_mfma_f32_16x16x32_bf16(kh1, qfl, s1, 0, 0, 0);
        s1 = __builtin_amdgcn_mfma_f32_16x16x32_bf16(kh1, qfh, s1, 0, 0, 0);

        // p = exp(s); scores bounded (~34), clamp is pure safety
        float p0[4], p1[4], sl = 0.f;
#pragma unroll
        for (int r = 0; r < 4; ++r) { p0[r] = __expf(fminf(s0[r], 60.f)); sl += p0[r]; }
#pragma unroll
        for (int r = 0; r < 4; ++r) { p1[r] = __expf(fminf(s1[r], 60.f)); sl += p1[r]; }
        sl += __shfl_xor(sl, 16);
        sl += __shfl_xor(sl, 32);
        l_run += sl;   // per-lane copy of its query's denominator

        // stage P[q][j] in LDS (padded stride 40 elems = 80 B)
        ushort4v w0, w1;
#pragma unroll
        for (int r = 0; r < 4; ++r) { w0[r] = f2b(p0[r]); w1[r] = f2b(p1[r]); }
        *(ushort4v*)(plds + col * 40 + g * 4)      = w0;  // keys g*4..+3
        *(ushort4v*)(plds + col * 40 + 16 + g * 4) = w1;  // keys 16+g*4..+3
        asm volatile("s_waitcnt lgkmcnt(0)" ::: "memory");
        __builtin_amdgcn_sched_barrier(0);

        // B-frag for PV: B[j][q] (one ds_read_b128, feeds all 16 MFMAs)
        short8 pf = *(const short8*)(plds + col * 40 + g * 8);
        asm volatile("" ::: "memory");   // next iter's writes stay below

        const unsigned short* vrow = vb + (size_t)col * N_ + j0 + g * 8;
#pragma unroll
        for (int t = 0; t < 16; ++t) {
            short8 vf = *(const short8*)(vrow + (size_t)t * 16 * N_);  // V[d][j]
            acc[t] = __builtin_amdgcn_mfma_f32_16x16x32_bf16(vf, pf, acc[t], 0, 0, 0);
        }
    }

    // epilogue: O[d][q]/l * gamma + x, f32 store in permuted layout
    float inv_l = 1.0f / l_run;
    float gam = gamma_p[0];
    int n = q0 + col;
    int s = n & (S_ - 1), kk = n >> 6;
    const float* xrow = x + (((size_t)(b * S_ + s)) * K_ + kk) * D_;
    float* orow = out + (((size_t)(b * S_ + s)) * K_ + kk) * D_;
#pragma unroll
    for (int t = 0; t < 16; ++t) {
        int d0 = t * 16 + g * 4;      // lane holds d = t*16 + g*4 + r, query n
        f32x4 xv = *(const f32x4*)(xrow + d0);
        f32x4 ov;
#pragma unroll
        for (int r = 0; r < 4; ++r)
            ov[r] = gam * acc[t][r] * inv_l + xv[r];
        *(f32x4*)(orow + d0) = ov;
    }
}

extern "C" void kernel_launch(void* const* d_in, const int* in_sizes, int n_in,
                              void* d_out, int out_size, void* d_ws, size_t ws_size,
                              hipStream_t stream) {
    const float* x  = (const float*)d_in[0];
    const float* Wq = (const float*)d_in[1];
    const float* bq = (const float*)d_in[2];
    const float* Wk = (const float*)d_in[3];
    const float* bk = (const float*)d_in[4];
    const float* Wv = (const float*)d_in[5];
    const float* bv = (const float*)d_in[6];
    const float* gm = (const float*)d_in[7];

    unsigned short* Qh = (unsigned short*)d_ws;                 // [B][N][C] 512KB
    unsigned short* Ql = Qh + (size_t)B_ * N_ * C_;
    unsigned short* Kh = Ql + (size_t)B_ * N_ * C_;
    unsigned short* Kl = Kh + (size_t)B_ * N_ * C_;
    unsigned short* Vm = Kl + (size_t)B_ * N_ * C_;             // [B][D][N] 4MB
    float* o = (float*)d_out;

    qkv_kernel<<<2560, 256, 0, stream>>>(x, Wq, bq, Wk, bk, Wv, bv,
                                         Qh, Ql, Kh, Kl, Vm);
    attn_kernel<<<512, 64, 0, stream>>>(Qh, Ql, Kh, Kl, Vm, x, gm, o);
}

// Round 4
// 256.754 us; speedup vs baseline: 2.1845x; 2.1845x over previous
//
#include <hip/hip_runtime.h>
#include <stdint.h>
#include <math.h>

using short8   = __attribute__((ext_vector_type(8))) short;
using ushort4v = __attribute__((ext_vector_type(4))) unsigned short;
using f32x4    = __attribute__((ext_vector_type(4))) float;

#define B_ 2
#define S_ 64
#define K_ 64
#define D_ 256
#define C_ 32
#define N_ 4096  /* S_*K_ */

__device__ __forceinline__ float b2f(unsigned short u) {
    unsigned int v = ((unsigned int)u) << 16;
    return __builtin_bit_cast(float, v);
}
__device__ __forceinline__ unsigned short f2b(float f) {   // RNE f32->bf16
    unsigned int x = __builtin_bit_cast(unsigned int, f);
    x += 0x7fffu + ((x >> 16) & 1u);
    return (unsigned short)(x >> 16);
}

// load 8 consecutive f32, produce hi/lo split-bf16 fragments (hi+lo ~ 2^-17 rel)
__device__ __forceinline__ void cvt8(const float* p, short8& hi, short8& lo) {
    f32x4 a = *(const f32x4*)p;
    f32x4 c = *(const f32x4*)(p + 4);
#pragma unroll
    for (int e = 0; e < 4; ++e) {
        unsigned short h0 = f2b(a[e]);
        hi[e]     = (short)h0; lo[e]     = (short)f2b(a[e] - b2f(h0));
        unsigned short h1 = f2b(c[e]);
        hi[e + 4] = (short)h1; lo[e + 4] = (short)f2b(c[e] - b2f(h1));
    }
}
__device__ __forceinline__ void cvt8h(const float* p, short8& hi) {
    f32x4 a = *(const f32x4*)p;
    f32x4 c = *(const f32x4*)(p + 4);
#pragma unroll
    for (int e = 0; e < 4; ++e) {
        hi[e]     = (short)f2b(a[e]);
        hi[e + 4] = (short)f2b(c[e]);
    }
}

// ---------------------------------------------------------------------------
// Kernel 1: QKV projections from f32 x, W. One wave = 16-token x 16-channel.
// ct 0-1 -> Q (hi/lo split), 2-3 -> K (hi/lo), 4-19 -> V (single bf16).
// Q,K stored [B][N][C] bf16 (hi and lo planes); V stored [B][D][N] bf16.
// ---------------------------------------------------------------------------
__global__ __launch_bounds__(256) void qkv_kernel(
    const float* __restrict__ x,
    const float* __restrict__ Wq, const float* __restrict__ bq,
    const float* __restrict__ Wk, const float* __restrict__ bk,
    const float* __restrict__ Wv, const float* __restrict__ bv,
    unsigned short* __restrict__ Qh, unsigned short* __restrict__ Ql,
    unsigned short* __restrict__ Kh, unsigned short* __restrict__ Kl,
    unsigned short* __restrict__ Vm)
{
    int widx = blockIdx.x * 4 + (threadIdx.x >> 6);   // 0..10239
    int lane = threadIdx.x & 63;
    int ttile = widx / 20;        // token tile of 16 (0..511)
    int ct    = widx % 20;        // channel tile
    int b  = ttile >> 8;
    int n0 = (ttile & 255) << 4;
    int col = lane & 15, g = lane >> 4;

    int n = n0 + col;
    int s = n & (S_ - 1), kk = n >> 6;
    const float* xrow = x + (((size_t)(b * S_ + s)) * K_ + kk) * D_;

    f32x4 acc = {0.f, 0.f, 0.f, 0.f};

    if (ct < 4) {                       // Q or K: hi/lo split path
        const float* W; const float* bias; int c0;
        if (ct < 2) { W = Wq; bias = bq; c0 = ct * 16; }
        else        { W = Wk; bias = bk; c0 = (ct - 2) * 16; }
        const float* wrow = W + (size_t)(c0 + col) * D_;
#pragma unroll
        for (int dc = 0; dc < 8; ++dc) {
            short8 xh, xl, wh, wl;
            cvt8(xrow + dc * 32 + g * 8, xh, xl);
            cvt8(wrow + dc * 32 + g * 8, wh, wl);
            acc = __builtin_amdgcn_mfma_f32_16x16x32_bf16(xl, wh, acc, 0, 0, 0);
            acc = __builtin_amdgcn_mfma_f32_16x16x32_bf16(xh, wl, acc, 0, 0, 0);
            acc = __builtin_amdgcn_mfma_f32_16x16x32_bf16(xh, wh, acc, 0, 0, 0);
        }
        float bb = bias[c0 + col];
        unsigned short* Th = (ct < 2) ? Qh : Kh;
        unsigned short* Tl = (ct < 2) ? Ql : Kl;
#pragma unroll
        for (int r = 0; r < 4; ++r) {
            int tok = n0 + g * 4 + r;
            float v = acc[r] + bb;
            unsigned short h = f2b(v);
            size_t idx = ((size_t)b * N_ + tok) * C_ + c0 + col;
            Th[idx] = h;
            Tl[idx] = f2b(v - b2f(h));
        }
    } else {                            // V: single-bf16 path
        int c0 = (ct - 4) * 16;
        const float* wrow = Wv + (size_t)(c0 + col) * D_;
#pragma unroll
        for (int dc = 0; dc < 8; ++dc) {
            short8 xh, wh;
            cvt8h(xrow + dc * 32 + g * 8, xh);
            cvt8h(wrow + dc * 32 + g * 8, wh);
            acc = __builtin_amdgcn_mfma_f32_16x16x32_bf16(xh, wh, acc, 0, 0, 0);
        }
        float bb = bv[c0 + col];
        ushort4v st;
#pragma unroll
        for (int r = 0; r < 4; ++r) st[r] = f2b(acc[r] + bb);
        *(ushort4v*)(Vm + ((size_t)b * D_ + c0 + col) * N_ + n0 + g * 4) = st;
    }
}

// ---------------------------------------------------------------------------
// Kernel 2: flash attention, in-block KV-split for occupancy.
// 512 blocks x 8 waves. All waves share the block's 16 queries; wave w owns
// keys [w*512, w*512+512). No-max softmax (scores bounded ~34) => partials
// combine by plain addition: LDS atomicAdd into accs[d][q] (stride 17),
// then cooperative epilogue (/l, gamma, residual, permuted f32 store).
// ---------------------------------------------------------------------------
__global__ __launch_bounds__(512, 4) void attn_kernel(
    const unsigned short* __restrict__ Qh, const unsigned short* __restrict__ Ql,
    const unsigned short* __restrict__ Kh, const unsigned short* __restrict__ Kl,
    const unsigned short* __restrict__ Vm, const float* __restrict__ x,
    const float* __restrict__ gamma_p, float* __restrict__ out)
{
    __shared__ unsigned short plds[8][16 * 40];  // per-wave P^T, padded stride 40
    __shared__ float accs[D_ * 17];              // [d][q] stride 17 (bank spread)
    __shared__ float lsum[16];

    int tid  = threadIdx.x;
    int wave = tid >> 6;
    int lane = tid & 63;
    int col = lane & 15, g = lane >> 4;

    int bid = blockIdx.x;                   // 512 % 8 == 0 -> bijective swizzle
    int swz = (bid & 7) * 64 + (bid >> 3);
    int b    = swz >> 8;
    int q0   = (swz & 255) << 4;

    // zero the combine buffers
    for (int i = tid; i < D_ * 17; i += 512) accs[i] = 0.f;
    if (tid < 16) lsum[tid] = 0.f;
    __syncthreads();

    // Q fragments: B[c][q] = Q[q][c], lane col = q, k = g*8+e
    size_t qoff = ((size_t)b * N_ + q0 + col) * C_ + g * 8;
    short8 qfh = *(const short8*)(Qh + qoff);
    short8 qfl = *(const short8*)(Ql + qoff);

    f32x4 acc[16];
#pragma unroll
    for (int t = 0; t < 16; ++t) acc[t] = (f32x4){0.f, 0.f, 0.f, 0.f};
    float l_run = 0.f;

    const unsigned short* kbh = Kh + (size_t)b * N_ * C_;
    const unsigned short* kbl = Kl + (size_t)b * N_ * C_;
    const unsigned short* vb  = Vm + (size_t)b * D_ * N_;
    unsigned short* pw = plds[wave];

    int jbase = wave * (N_ / 8);            // this wave's 512-key chunk
    for (int it = 0; it < N_ / 8; it += 32) {
        int j0 = jbase + it;
        size_t k0 = (size_t)(j0 + col) * C_ + g * 8;
        size_t k1 = (size_t)(j0 + 16 + col) * C_ + g * 8;
        short8 kh0 = *(const short8*)(kbh + k0);
        short8 kl0 = *(const short8*)(kbl + k0);
        short8 kh1 = *(const short8*)(kbh + k1);
        short8 kl1 = *(const short8*)(kbl + k1);

        f32x4 z = {0.f, 0.f, 0.f, 0.f};
        f32x4 s0 = __builtin_amdgcn_mfma_f32_16x16x32_bf16(kl0, qfh, z, 0, 0, 0);
        s0 = __builtin_amdgcn_mfma_f32_16x16x32_bf16(kh0, qfl, s0, 0, 0, 0);
        s0 = __builtin_amdgcn_mfma_f32_16x16x32_bf16(kh0, qfh, s0, 0, 0, 0);
        f32x4 s1 = __builtin_amdgcn_mfma_f32_16x16x32_bf16(kl1, qfh, z, 0, 0, 0);
        s1 = __builtin_amdgcn_mfma_f32_16x16x32_bf16(kh1, qfl, s1, 0, 0, 0);
        s1 = __builtin_amdgcn_mfma_f32_16x16x32_bf16(kh1, qfh, s1, 0, 0, 0);

        // p = exp(s); scores bounded (~34), clamp is pure safety
        float p0[4], p1[4], sl = 0.f;
#pragma unroll
        for (int r = 0; r < 4; ++r) { p0[r] = __expf(fminf(s0[r], 60.f)); sl += p0[r]; }
#pragma unroll
        for (int r = 0; r < 4; ++r) { p1[r] = __expf(fminf(s1[r], 60.f)); sl += p1[r]; }
        sl += __shfl_xor(sl, 16);
        sl += __shfl_xor(sl, 32);
        l_run += sl;   // per-lane copy of its query's chunk denominator

        // stage P[q][j] in this wave's LDS buffer (padded stride 40)
        ushort4v w0, w1;
#pragma unroll
        for (int r = 0; r < 4; ++r) { w0[r] = f2b(p0[r]); w1[r] = f2b(p1[r]); }
        *(ushort4v*)(pw + col * 40 + g * 4)      = w0;  // keys g*4..+3
        *(ushort4v*)(pw + col * 40 + 16 + g * 4) = w1;  // keys 16+g*4..+3
        asm volatile("s_waitcnt lgkmcnt(0)" ::: "memory");
        __builtin_amdgcn_sched_barrier(0);

        // B-frag for PV: B[j][q] (one ds_read_b128, feeds all 16 MFMAs)
        short8 pf = *(const short8*)(pw + col * 40 + g * 8);
        asm volatile("" ::: "memory");   // next iter's writes stay below

        const unsigned short* vrow = vb + (size_t)col * N_ + j0 + g * 8;
#pragma unroll
        for (int t = 0; t < 16; ++t) {
            short8 vf = *(const short8*)(vrow + (size_t)t * 16 * N_);  // V[d][j]
            acc[t] = __builtin_amdgcn_mfma_f32_16x16x32_bf16(vf, pf, acc[t], 0, 0, 0);
        }
    }

    // combine partials across waves (plain sums: no-max softmax)
#pragma unroll
    for (int t = 0; t < 16; ++t)
#pragma unroll
        for (int r = 0; r < 4; ++r) {
            int d = t * 16 + g * 4 + r;          // lane holds O[d][q=col]
            atomicAdd(&accs[d * 17 + col], acc[t][r]);
        }
    if (lane < 16) atomicAdd(&lsum[lane], l_run);
    __syncthreads();

    // epilogue: each wave handles 2 queries; lanes cover d (stride 32)
    int qi = wave * 2 + (lane >> 5);   // 0..15
    int li = lane & 31;
    int n = q0 + qi;
    int s = n & (S_ - 1), kk = n >> 6;
    const float* xrow = x + (((size_t)(b * S_ + s)) * K_ + kk) * D_;
    float* orow = out + (((size_t)(b * S_ + s)) * K_ + kk) * D_;
    float inv_l = 1.0f / lsum[qi];
    float gam = gamma_p[0];
#pragma unroll
    for (int k = 0; k < 8; ++k) {
        int d = li + k * 32;
        orow[d] = gam * accs[d * 17 + qi] * inv_l + xrow[d];
    }
}

extern "C" void kernel_launch(void* const* d_in, const int* in_sizes, int n_in,
                              void* d_out, int out_size, void* d_ws, size_t ws_size,
                              hipStream_t stream) {
    const float* x  = (const float*)d_in[0];
    const float* Wq = (const float*)d_in[1];
    const float* bq = (const float*)d_in[2];
    const float* Wk = (const float*)d_in[3];
    const float* bk = (const float*)d_in[4];
    const float* Wv = (const float*)d_in[5];
    const float* bv = (const float*)d_in[6];
    const float* gm = (const float*)d_in[7];

    unsigned short* Qh = (unsigned short*)d_ws;                 // [B][N][C] 512KB
    unsigned short* Ql = Qh + (size_t)B_ * N_ * C_;
    unsigned short* Kh = Ql + (size_t)B_ * N_ * C_;
    unsigned short* Kl = Kh + (size_t)B_ * N_ * C_;
    unsigned short* Vm = Kl + (size_t)B_ * N_ * C_;             // [B][D][N] 4MB
    float* o = (float*)d_out;

    qkv_kernel<<<2560, 256, 0, stream>>>(x, Wq, bq, Wk, bk, Wv, bv,
                                         Qh, Ql, Kh, Kl, Vm);
    attn_kernel<<<512, 512, 0, stream>>>(Qh, Ql, Kh, Kl, Vm, x, gm, o);
}